// Round 2
// baseline (233.071 us; speedup 1.0000x reference)
//
#include <hip/hip_runtime.h>
#include <math.h>

#define EPSF 1e-9f

// ---------------------------------------------------------------------------
// Kernel 1: streaming pass. grid = 512 (b = bid>>1, t-half = bid&1), 1024 thr.
// Each block handles 24 t-rows of out_ids/trg_labels for one batch b.
// trg_labels rows are exact one-hots -> (out*lab).sum() == out[hot], mask==hot
// found. So NO per-t cross-lane reduction: private accumulate, one reduce at
// the end. dist_r partials written to ws (non-atomic).
// acc[0]=id_num, acc[1]=id_mask_cnt, acc[2]=kl_sum.
// ---------------------------------------------------------------------------
__global__ __launch_bounds__(1024) void e2e3_stream(
    const float* __restrict__ out_ids,      // [48,256,4096]
    const float* __restrict__ trg_labels,   // [50,256,4096]
    float* __restrict__ dist_part,          // [2,256,4096]
    float* __restrict__ acc)
{
    const int bid  = blockIdx.x;
    const int b    = bid >> 1;
    const int h    = bid & 1;
    const int tid  = threadIdx.x;
    const int wave = tid >> 6;
    const int lane = tid & 63;
    const int v0   = tid << 2;
    const int t0   = h * 24;

    const size_t tstride = (size_t)256 * 4096;
    const float* outp = out_ids    + (size_t)t0 * tstride       + (size_t)b * 4096 + v0;
    const float* labp = trg_labels + (size_t)(t0 + 1) * tstride + (size_t)b * 4096 + v0;

    float4 dist = make_float4(0.f, 0.f, 0.f, 0.f);
    float idnum = 0.f, idcnt = 0.f;

    float4 o = *reinterpret_cast<const float4*>(outp);
    float4 l = *reinterpret_cast<const float4*>(labp);
    for (int t = 0; t < 24; ++t) {
        float4 o2 = o, l2 = l;
        if (t < 23) {
            o2 = *reinterpret_cast<const float4*>(outp + (size_t)(t + 1) * tstride);
            l2 = *reinterpret_cast<const float4*>(labp + (size_t)(t + 1) * tstride);
        }
        dist.x += o.x; dist.y += o.y; dist.z += o.z; dist.w += o.w;
        if (l.x > 0.5f) { idnum -= logf(fmaxf(o.x, EPSF)); idcnt += 1.f; }
        if (l.y > 0.5f) { idnum -= logf(fmaxf(o.y, EPSF)); idcnt += 1.f; }
        if (l.z > 0.5f) { idnum -= logf(fmaxf(o.z, EPSF)); idcnt += 1.f; }
        if (l.w > 0.5f) { idnum -= logf(fmaxf(o.w, EPSF)); idcnt += 1.f; }
        o = o2; l = l2;
    }

    *reinterpret_cast<float4*>(dist_part + ((size_t)h * 256 + b) * 4096 + v0) = dist;

    __shared__ float red[2][16];
    #pragma unroll
    for (int off = 32; off >= 1; off >>= 1) {
        idnum += __shfl_down(idnum, off, 64);
        idcnt += __shfl_down(idcnt, off, 64);
    }
    if (lane == 0) { red[0][wave] = idnum; red[1][wave] = idcnt; }
    __syncthreads();
    if (tid == 0) {
        float a = 0.f, c = 0.f;
        #pragma unroll
        for (int w = 0; w < 16; ++w) { a += red[0][w]; c += red[1][w]; }
        atomicAdd(&acc[0], a);
        atomicAdd(&acc[1], c);
    }
}

// ---------------------------------------------------------------------------
// Kernel 2: per-b candidate-union dedup + Pm + Pb + KL. grid 256 x 256 thr.
// ---------------------------------------------------------------------------
__global__ __launch_bounds__(256) void e2e3_kl(
    const float* __restrict__ selector_probs,   // [256,64]
    const int*   __restrict__ candi_ids,        // [256,64]
    const int*   __restrict__ routes,           // [256,4096]
    const float* __restrict__ dist_part,        // [2,256,4096]
    float* __restrict__ acc)
{
    const int b   = blockIdx.x;
    const int tid = threadIdx.x;

    __shared__ int   ids_s[64];
    __shared__ int   rep_s[64];
    __shared__ float valid_s[64];
    __shared__ float pmlog_s[64];
    __shared__ float agg_s[64];

    if (tid < 64)               ids_s[tid] = candi_ids[b * 64 + tid];
    if (tid >= 64 && tid < 128) agg_s[tid - 64] = 0.f;
    __syncthreads();

    if (tid < 64) {
        const int my = ids_s[tid];
        int r = tid;
        for (int j = 0; j < 64; ++j) { if (ids_s[j] == my) { r = j; break; } }
        rep_s[tid]   = r;
        valid_s[tid] = (r == tid) ? 1.f : 0.f;
    }
    __syncthreads();

    if (tid < 64) {
        float pm = 0.f;
        for (int i = 0; i < 64; ++i)
            if (rep_s[i] == tid) pm += selector_probs[b * 64 + i];
        float tot = pm;
        #pragma unroll
        for (int off = 32; off >= 1; off >>= 1) tot += __shfl_xor(tot, off, 64);
        pm = pm / fmaxf(tot, EPSF);
        pmlog_s[tid] = logf(fmaxf(pm, EPSF));
    }
    __syncthreads();

    // agg[u] += dist_r[b,v] for first slot u with ids[u]==routes[b,v]
    const float* dp0 = dist_part + (size_t)b * 4096;
    const float* dp1 = dist_part + ((size_t)256 + b) * 4096;
    #pragma unroll
    for (int it = 0; it < 4; ++it) {
        const int v = it * 1024 + tid * 4;
        const float4 d0 = *reinterpret_cast<const float4*>(dp0 + v);
        const float4 d1 = *reinterpret_cast<const float4*>(dp1 + v);
        const int4   rv = *reinterpret_cast<const int4*>(routes + (size_t)b * 4096 + v);
        const float dv[4] = {d0.x + d1.x, d0.y + d1.y, d0.z + d1.z, d0.w + d1.w};
        const int   rr[4] = {rv.x, rv.y, rv.z, rv.w};
        #pragma unroll
        for (int k = 0; k < 4; ++k) {
            const int r = rr[k];
            for (int u = 0; u < 64; ++u) {
                if (ids_s[u] == r) { atomicAdd(&agg_s[u], dv[k]); break; }
            }
        }
    }
    __syncthreads();

    if (tid < 64) {
        const float va = valid_s[tid];
        const float a  = (va > 0.5f) ? agg_s[tid] : 0.f;   // invalid slots zeroed
        float s = a, uc = va;
        #pragma unroll
        for (int off = 32; off >= 1; off >>= 1) {
            s  += __shfl_xor(s,  off, 64);
            uc += __shfl_xor(uc, off, 64);
        }
        const float pb = (s > 0.f) ? (a / fmaxf(s, EPSF)) : (va / fmaxf(uc, 1.f));
        float term = 0.f;
        if (va > 0.5f) {
            const float pbc = fmaxf(pb, EPSF);
            term = pbc * (logf(pbc) - pmlog_s[tid]);
        }
        #pragma unroll
        for (int off = 32; off >= 1; off >>= 1) term += __shfl_down(term, off, 64);
        if (tid == 0) atomicAdd(&acc[2], term);
    }
}

// ---------------------------------------------------------------------------
// Kernel 3: small terms + final combine. Single block, 256 threads.
// ---------------------------------------------------------------------------
__global__ __launch_bounds__(256) void e2e3_small(
    const float* __restrict__ selector_probs,   // [256,64]
    const float* __restrict__ selector_onehot,  // [256,64]
    const float* __restrict__ out_rates,        // [48,256]
    const float* __restrict__ trg_rates,        // [50,256]
    const int*   __restrict__ trg_lengths,      // [256]
    const float* __restrict__ acc,              // [4]
    float* __restrict__ out)
{
    const int tid  = threadIdx.x;
    const int wave = tid >> 6;
    const int lane = tid & 63;

    float v_selnum = 0.f, v_selcnt = 0.f, v_ent = 0.f;
    float v_rate = 0.f, v_den = 0.f, v_smooth = 0.f;

    for (int g = tid; g < 512; g += 256) {
        const float* pp = selector_probs  + g * 32;
        const float* oo = selector_onehot + g * 32;
        float p = 0.f, m = 0.f;
        #pragma unroll
        for (int k = 0; k < 32; ++k) { p += pp[k] * oo[k]; m += oo[k]; }
        if (m > 0.5f) { v_selnum += -logf(fmaxf(p, EPSF)); v_selcnt += 1.f; }
    }
    for (int i = tid; i < 256 * 64; i += 256) {
        const float p = fmaxf(selector_probs[i], EPSF);
        v_ent += -p * logf(p);
    }
    for (int i = tid; i < 48 * 256; i += 256)
        v_rate += fabsf(out_rates[i] - trg_rates[i + 256]);
    for (int b2 = tid; b2 < 256; b2 += 256)
        v_den += (float)(trg_lengths[b2] - 2);
    for (int i = tid; i < 47 * 256; i += 256) {
        const int b2 = i & 255;
        const int t  = i >> 8;
        int eff = trg_lengths[b2] - 3; if (eff < 0) eff = 0;
        if (t < eff) v_smooth += fabsf(out_rates[i + 256] - out_rates[i]);
    }

    __shared__ float red[6][4];
    float vals[6] = {v_selnum, v_selcnt, v_ent, v_rate, v_den, v_smooth};
    #pragma unroll
    for (int k = 0; k < 6; ++k) {
        float v = vals[k];
        #pragma unroll
        for (int off = 32; off >= 1; off >>= 1) v += __shfl_down(v, off, 64);
        if (lane == 0) red[k][wave] = v;
    }
    __syncthreads();
    if (tid == 0) {
        float s[6];
        #pragma unroll
        for (int k = 0; k < 6; ++k) s[k] = red[k][0] + red[k][1] + red[k][2] + red[k][3];
        const float loss =
              s[0] / fmaxf(s[1], 1.f)                      // LAM_SEL * loss_sel
            + 10.f * acc[0] / fmaxf(acc[1], 1.f)           // loss_id
            + 5.f  * s[3]   / fmaxf(s[4], 1.f)             // loss_rate
            + 0.1f * acc[2] * (1.f / 256.f)                // loss_kl
            + 0.05f * 0.5f * s[2] * (1.f / 256.f)          // loss_entropy
            + 0.5f * s[5];                                 // loss_smooth
        out[0] = loss;
    }
}

extern "C" void kernel_launch(void* const* d_in, const int* in_sizes, int n_in,
                              void* d_out, int out_size, void* d_ws, size_t ws_size,
                              hipStream_t stream) {
    const float* selector_probs  = (const float*)d_in[1];
    const float* selector_onehot = (const float*)d_in[2];
    const float* out_ids         = (const float*)d_in[3];
    const float* out_rates       = (const float*)d_in[4];
    const float* trg_labels      = (const float*)d_in[5];
    const float* trg_rates       = (const float*)d_in[6];
    const int*   trg_lengths     = (const int*)d_in[7];
    const int*   candi_ids       = (const int*)d_in[8];
    const int*   routes          = (const int*)d_in[9];

    float* acc       = (float*)d_ws;                       // 4 floats
    float* dist_part = (float*)((char*)d_ws + 256);        // [2,256,4096] = 8 MB

    hipMemsetAsync(acc, 0, 4 * sizeof(float), stream);

    e2e3_stream<<<512, 1024, 0, stream>>>(out_ids, trg_labels, dist_part, acc);
    e2e3_kl<<<256, 256, 0, stream>>>(selector_probs, candi_ids, routes,
                                     dist_part, acc);
    e2e3_small<<<1, 256, 0, stream>>>(selector_probs, selector_onehot,
                                      out_rates, trg_rates, trg_lengths,
                                      acc, (float*)d_out);
}